// Round 15
// baseline (2049.132 us; speedup 1.0000x reference)
//
#include <hip/hip_runtime.h>

// Seq2Seq attention-LSTM decoder, B=32, T_ENC=512, H=E=ENC_H=512, V=32000, STEPS=64.
// Round 15: k_fused reverted to round-13 (proven 1071 us; RMW-counter group
// barrier). splitA stays fused in the Wp GEMM epilogue. k_mfma: 2 m-tiles per
// block (grid 8x250) so Wo f32->bf16 conversion + L2 reads are shared (16x->8x
// redundancy). Logits split math and exact-argmax rescue unchanged.

#define NEGF (-3.4028235e38f)

typedef short bf8 __attribute__((ext_vector_type(8)));
typedef unsigned short us8 __attribute__((ext_vector_type(8)));
typedef float f32x4 __attribute__((ext_vector_type(4)));

static __device__ __forceinline__ float sigf(float x) { return 1.0f / (1.0f + expf(-x)); }

static __device__ __forceinline__ float aload(const float* p) {
    return __hip_atomic_load(p, __ATOMIC_RELAXED, __HIP_MEMORY_SCOPE_AGENT);
}
static __device__ __forceinline__ void astore(float* p, float v) {
    __hip_atomic_store(p, v, __ATOMIC_RELAXED, __HIP_MEMORY_SCOPE_AGENT);
}
static __device__ __forceinline__ unsigned fordkey(float f) {
    unsigned u = __float_as_uint(f);
    return (u & 0x80000000u) ? ~u : (u | 0x80000000u);
}
static __device__ __forceinline__ unsigned short f2bf(float x) {  // RNE
    unsigned u = __float_as_uint(x);
    return (unsigned short)((u + 0x7FFFu + ((u >> 16) & 1u)) >> 16);
}
static __device__ __forceinline__ float bf2f(unsigned short b) {
    return __uint_as_float(((unsigned)b) << 16);
}

// ---- split group barrier: 8 blocks/group, monotonic counter, relaxed -------
static __device__ __forceinline__ void bar_arrive(unsigned* ctr) {
    __syncthreads();
    if (threadIdx.x == 0) {
        asm volatile("s_waitcnt vmcnt(0)" ::: "memory");
        __hip_atomic_fetch_add(ctr, 1u, __ATOMIC_RELAXED, __HIP_MEMORY_SCOPE_AGENT);
    }
}
static __device__ __forceinline__ void bar_wait(unsigned* ctr, unsigned target) {
    if (threadIdx.x == 0) {
        while ((int)(__hip_atomic_load(ctr, __ATOMIC_RELAXED, __HIP_MEMORY_SCOPE_AGENT)
                     - target) < 0) {
            __builtin_amdgcn_s_sleep(1);
        }
    }
    __syncthreads();
}

// dst[c*rows + r] = src[r*ld + coff + c]
__global__ __launch_bounds__(256) void k_transpose(const float* __restrict__ src,
    float* __restrict__ dst, int rows, int cols, int ld, int coff)
{
    __shared__ float tile[32][33];
    int c0 = blockIdx.x * 32, r0 = blockIdx.y * 32;
    int tx = threadIdx.x & 31, ty = threadIdx.x >> 5;
#pragma unroll
    for (int i = 0; i < 32; i += 8)
        tile[ty + i][tx] = src[(size_t)(r0 + ty + i) * ld + coff + c0 + tx];
    __syncthreads();
#pragma unroll
    for (int i = 0; i < 32; i += 8)
        dst[(size_t)(c0 + ty + i) * rows + r0 + tx] = tile[tx][ty + i];
}

// dst[b,j] = dot(vec[b,:], W[j,:]); writes row-major (optional) + transposed
__global__ __launch_bounds__(512) void k_init_state(const float* __restrict__ vec,
    const float* __restrict__ W, float* __restrict__ dst, float* __restrict__ dstT)
{
    int b = blockIdx.x, j = threadIdx.x;
    __shared__ float sv[512];
    sv[j] = vec[b * 512 + j];
    __syncthreads();
    const float* wr = W + (size_t)j * 512;
    float a0 = 0, a1 = 0, a2 = 0, a3 = 0;
#pragma unroll 4
    for (int k = 0; k < 512; k += 4) {
        float4 w = *reinterpret_cast<const float4*>(wr + k);
        a0 += sv[k] * w.x; a1 += sv[k + 1] * w.y;
        a2 += sv[k + 2] * w.z; a3 += sv[k + 3] * w.w;
    }
    float v = (a0 + a1) + (a2 + a3);
    if (dst) dst[b * 512 + j] = v;
    dstT[j * 32 + b] = v;
}

// emb_seq[m=t*32+b, :] = (t==0) ? 0 : embedding[trg[b, t-1], :]
__global__ __launch_bounds__(256) void k_gather(const int* __restrict__ trg,
    const float* __restrict__ emb, float* __restrict__ eseq)
{
    int gid = blockIdx.x * 256 + threadIdx.x;
    int m = gid >> 7, e4 = gid & 127;
    int t = m >> 5, b = m & 31;
    float4 v = make_float4(0.f, 0.f, 0.f, 0.f);
    if (t > 0) {
        int row = trg[b * 64 + (t - 1)];
        v = *reinterpret_cast<const float4*>(emb + (size_t)row * 512 + e4 * 4);
    }
    *reinterpret_cast<float4*>(eseq + (size_t)m * 512 + e4 * 4) = v;
}

// fp32 GEMM (small mats): C[M,N] = A*B^T (+bias). 256x128 tile, 16x8 micro.
// asp != nullptr: also emit bf16 [hi|lo] split of C rows into asp[M][1024].
__global__ __launch_bounds__(256) void k_gemm_nt(const float* __restrict__ A, int lda,
    size_t strideA, const float* __restrict__ B, int ldb, const float* __restrict__ bias,
    float* __restrict__ C, size_t strideC, int N, int K, unsigned short* __restrict__ asp)
{
    __shared__ float sA[32][260];
    __shared__ float sB[32][132];
    A += strideA * blockIdx.z;
    C += strideC * blockIdx.z;
    int tid = threadIdx.x;
    int m0 = blockIdx.x * 256, n0 = blockIdx.y * 128;
    int tx = tid & 15, ty = tid >> 4;
    float acc[16][8] = {};
    for (int k0 = 0; k0 < K; k0 += 32) {
#pragma unroll
        for (int i = 0; i < 8; ++i) {
            int f4 = tid + i * 256;
            int r = f4 >> 3, c4 = f4 & 7;
            float4 va = *reinterpret_cast<const float4*>(A + (size_t)(m0 + r) * lda + k0 + c4 * 4);
            sA[c4 * 4 + 0][r] = va.x; sA[c4 * 4 + 1][r] = va.y;
            sA[c4 * 4 + 2][r] = va.z; sA[c4 * 4 + 3][r] = va.w;
        }
#pragma unroll
        for (int i = 0; i < 4; ++i) {
            int f4 = tid + i * 256;
            int r = f4 >> 3, c4 = f4 & 7;
            float4 vb = *reinterpret_cast<const float4*>(B + (size_t)(n0 + r) * ldb + k0 + c4 * 4);
            sB[c4 * 4 + 0][r] = vb.x; sB[c4 * 4 + 1][r] = vb.y;
            sB[c4 * 4 + 2][r] = vb.z; sB[c4 * 4 + 3][r] = vb.w;
        }
        __syncthreads();
#pragma unroll 4
        for (int k = 0; k < 32; ++k) {
            float a[16], b[8];
            *reinterpret_cast<float4*>(&a[0])  = *reinterpret_cast<const float4*>(&sA[k][ty * 16]);
            *reinterpret_cast<float4*>(&a[4])  = *reinterpret_cast<const float4*>(&sA[k][ty * 16 + 4]);
            *reinterpret_cast<float4*>(&a[8])  = *reinterpret_cast<const float4*>(&sA[k][ty * 16 + 8]);
            *reinterpret_cast<float4*>(&a[12]) = *reinterpret_cast<const float4*>(&sA[k][ty * 16 + 12]);
            *reinterpret_cast<float4*>(&b[0]) = *reinterpret_cast<const float4*>(&sB[k][tx * 8]);
            *reinterpret_cast<float4*>(&b[4]) = *reinterpret_cast<const float4*>(&sB[k][tx * 8 + 4]);
#pragma unroll
            for (int i = 0; i < 16; ++i)
#pragma unroll
                for (int j = 0; j < 8; ++j)
                    acc[i][j] += a[i] * b[j];
        }
        __syncthreads();
    }
#pragma unroll
    for (int i = 0; i < 16; ++i) {
        int row = m0 + ty * 16 + i;
        float* cp = C + (size_t)row * N + n0 + tx * 8;
        float v[8];
#pragma unroll
        for (int j = 0; j < 8; ++j) v[j] = acc[i][j];
        if (bias) {
            const float* bb = bias + n0 + tx * 8;
#pragma unroll
            for (int j = 0; j < 8; ++j) v[j] += bb[j];
        }
        *reinterpret_cast<float4*>(cp) = make_float4(v[0], v[1], v[2], v[3]);
        *reinterpret_cast<float4*>(cp + 4) = make_float4(v[4], v[5], v[6], v[7]);
        if (asp) {
            unsigned short hi[8], lo[8];
#pragma unroll
            for (int j = 0; j < 8; ++j) {
                hi[j] = f2bf(v[j]);
                lo[j] = f2bf(v[j] - bf2f(hi[j]));
            }
            unsigned short* ap = asp + (size_t)row * 1024 + n0 + tx * 8;
            *reinterpret_cast<us8*>(ap)       = *reinterpret_cast<const us8*>(hi);
            *reinterpret_cast<us8*>(ap + 512) = *reinterpret_cast<const us8*>(lo);
        }
    }
}

// bf16 MFMA logits GEMM: C[2048, 32000] = [Ahi|Alo] @ [Bhi|Bhi]^T + bo.
// Block covers 256 m x 128 n (2 m-tiles of 128); 256 thr (2x2 waves, 64x64
// per wave per m-tile). B staged+converted ONCE per k-block, reused by both
// m-tiles and both A segments. REMAP store + approx argmax/sumexp stats.
__global__ __launch_bounds__(256) void k_mfma(
    const unsigned short* __restrict__ Asp,  // [2048][1024] bf16 [hi|lo]
    const float* __restrict__ Wo,            // [32000][512] f32
    const float* __restrict__ bo,
    float* __restrict__ out0,
    unsigned long long* __restrict__ keyr, float* __restrict__ sumr)
{
    __shared__ unsigned short sAb[2][256 * 64];  // 64 KB (hi, lo) x 256 rows
    __shared__ unsigned short sBb[128 * 64];     // 16 KB
    int tid = threadIdx.x;
    int m0 = blockIdx.x * 256, n0 = blockIdx.y * 128;
    int l = tid & 63, wv = tid >> 6;
    int wr = wv >> 1, wc = wv & 1;
    int lm = l & 15, lg = l >> 4;

    f32x4 acc[2][4][4] = {};

    for (int kb = 0; kb < 8; ++kb) {
        // stage A hi+lo for both m-tiles (bf16 copy)
#pragma unroll
        for (int i = 0; i < 16; ++i) {
            int p = tid + i * 256;           // 0..4095
            int seg = p >> 11;               // 0:hi 1:lo
            int q2 = p & 2047;
            int row = q2 >> 3, pk = q2 & 7;  // row 0..255
            int widx = row * 64 + ((pk * 8) ^ ((row & 7) << 3));
            *reinterpret_cast<us8*>(&sAb[seg][widx]) =
                *reinterpret_cast<const us8*>(
                    Asp + (size_t)(m0 + row) * 1024 + seg * 512 + kb * 64 + pk * 8);
        }
        // stage B once (f32 -> bf16 hi convert)
#pragma unroll
        for (int i = 0; i < 4; ++i) {
            int p = tid + i * 256;
            int row = p >> 3, pk = p & 7;
            int widx = row * 64 + ((pk * 8) ^ ((row & 7) << 3));
            const float* bp = Wo + (size_t)(n0 + row) * 512 + kb * 64 + pk * 8;
            float4 b0 = *reinterpret_cast<const float4*>(bp);
            float4 b1 = *reinterpret_cast<const float4*>(bp + 4);
            unsigned short hw[8] = { f2bf(b0.x), f2bf(b0.y), f2bf(b0.z), f2bf(b0.w),
                                     f2bf(b1.x), f2bf(b1.y), f2bf(b1.z), f2bf(b1.w) };
            *reinterpret_cast<us8*>(&sBb[widx]) = *reinterpret_cast<const us8*>(hw);
        }
        __syncthreads();
#pragma unroll
        for (int ks = 0; ks < 2; ++ks) {
            bf8 bfr[4];
#pragma unroll
            for (int fc = 0; fc < 4; ++fc) {
                int row = wc * 64 + fc * 16 + lm;
                int idx = row * 64 + ((ks * 32 + lg * 8) ^ ((row & 7) << 3));
                bfr[fc] = *reinterpret_cast<const bf8*>(&sBb[idx]);
            }
#pragma unroll
            for (int mt = 0; mt < 2; ++mt) {
#pragma unroll
                for (int aseg = 0; aseg < 2; ++aseg) {
                    bf8 af[4];
#pragma unroll
                    for (int fr = 0; fr < 4; ++fr) {
                        int row = mt * 128 + wr * 64 + fr * 16 + lm;
                        int idx = row * 64 + ((ks * 32 + lg * 8) ^ ((row & 7) << 3));
                        af[fr] = *reinterpret_cast<const bf8*>(&sAb[aseg][idx]);
                    }
#pragma unroll
                    for (int fr = 0; fr < 4; ++fr)
#pragma unroll
                        for (int fc = 0; fc < 4; ++fc)
                            acc[mt][fr][fc] = __builtin_amdgcn_mfma_f32_16x16x32_bf16(
                                af[fr], bfr[fc], acc[mt][fr][fc], 0, 0, 0);
                }
            }
        }
        __syncthreads();
    }

    // epilogue per m-tile: bias + REMAP store + per-row approx stats
#pragma unroll
    for (int mt = 0; mt < 2; ++mt) {
#pragma unroll
        for (int fr = 0; fr < 4; ++fr) {
#pragma unroll
            for (int j = 0; j < 4; ++j) {
                int m = m0 + mt * 128 + wr * 64 + fr * 16 + lg * 4 + j;
                size_t crow = (size_t)((m & 31) * 64 + (m >> 5));
                float* cp = out0 + crow * 32000 + n0 + wc * 64 + lm;
                float vv[4];
                float mval = NEGF; int midx = 0; float esum = 0.f;
#pragma unroll
                for (int fc = 0; fc < 4; ++fc) {
                    int col = n0 + wc * 64 + fc * 16 + lm;
                    float v = acc[mt][fr][fc][j] + bo[col];
                    vv[fc] = v;
                    if (v > mval) { mval = v; midx = col; }
                    esum += expf(v);
                }
#pragma unroll
                for (int fc = 0; fc < 4; ++fc) cp[fc * 16] = vv[fc];
#pragma unroll
                for (int msk = 1; msk <= 8; msk <<= 1) {
                    float vo = __shfl_xor(mval, msk);
                    int   io = __shfl_xor(midx, msk);
                    float so = __shfl_xor(esum, msk);
                    esum += so;
                    if (vo > mval || (vo == mval && io < midx)) { mval = vo; midx = io; }
                }
                if (lm == 0) {
                    unsigned long long key =
                        ((unsigned long long)fordkey(mval) << 32) | (unsigned)(~(unsigned)midx);
                    atomicMax(&keyr[crow], key);
                    atomicAdd(&sumr[crow], esum);
                }
            }
        }
    }
}

// ---------------- fused 64-step decoder (cooperative, per-b groups) --------
// round-13 version, verbatim (proven 1071 us).
__global__ __launch_bounds__(1024) void k_fused(
    const float* __restrict__ WaT, const float* __restrict__ zemb,
    const float* __restrict__ cemb, const float* __restrict__ encWc,
    const float* __restrict__ Wih, const float* __restrict__ Whh,
    const float* __restrict__ bih, const float* __restrict__ bhh,
    float* __restrict__ h_g, const float* __restrict__ cT,
    float* __restrict__ z_g, float* __restrict__ combS,
    float* __restrict__ comb_g, float* __restrict__ states,
    unsigned* __restrict__ bar)
{
    __shared__ float eW[512][64];
    __shared__ float hsh[512];
    __shared__ float csh[512];
    __shared__ float zl[512];
    __shared__ float red16[16][64];
    __shared__ float wred[8];
    __shared__ float wred2[8];
    __shared__ float sgate[4][64];
    __shared__ float carr[64];

    int tid = threadIdx.x, bid = blockIdx.x;
    int b = bid >> 3, s = bid & 7;
    int jj = tid & 63, q = tid >> 6;
    unsigned* barb = bar + b * 32;
    unsigned nbar = 0;

    int wv = tid >> 6, lane = tid & 63;
    int rowid = wv * 16 + (lane >> 2);
    int g = rowid >> 6, jgl = rowid & 63;
    int kq = lane & 3;
    const float* whp = Whh + (size_t)(g * 512 + s * 64 + jgl) * 512;
    const float* wip = Wih + (size_t)(g * 512 + s * 64 + jgl) * 512;

    {
        const float* src = encWc + ((size_t)b << 18) + s * 64;
        for (int i = tid; i < 512 * 16; i += 1024) {
            int t = i >> 4, c4 = i & 15;
            float4 v = *reinterpret_cast<const float4*>(src + (size_t)t * 512 + c4 * 4);
            *reinterpret_cast<float4*>(&eW[t][c4 * 4]) = v;
        }
    }
    if (tid < 64) carr[tid] = cT[(s * 64 + tid) * 32 + b];

    for (int tstep = 0; tstep < 64; ++tstep) {
        if (tid < 512) hsh[tid] = aload(h_g + b * 512 + tid);
        __syncthreads();
        {
            float acc = 0.f;
            const float* hp = hsh + q * 32;
            const float* wp = WaT + (size_t)(q * 32) * 512 + s * 64 + jj;
#pragma unroll 8
            for (int k = 0; k < 32; ++k)
                acc += hp[k] * wp[(size_t)k * 512];
            red16[q][jj] = acc;
        }
        __syncthreads();
        if (tid < 64) {
            float v = 0.f;
#pragma unroll
            for (int r = 0; r < 16; ++r) v += red16[r][jj];
            v += zemb[((size_t)tstep * 32 + b) * 512 + s * 64 + jj];
            astore(z_g + b * 512 + s * 64 + jj, v);
        }
        ++nbar; bar_arrive(barb);

        float acc_hh = 0.f;
#pragma unroll 8
        for (int i = 0; i < 32; ++i) {
            int k = kq * 4 + i * 16;
            float4 v4 = *reinterpret_cast<const float4*>(whp + k);
            acc_hh += v4.x * hsh[k]     + v4.y * hsh[k + 1]
                    + v4.z * hsh[k + 2] + v4.w * hsh[k + 3];
        }
        bar_wait(barb, nbar * 8u);

        {
            float zv = 0.f;
            if (tid < 512) {
                zv = aload(z_g + b * 512 + tid);
                float m = zv;
#pragma unroll
                for (int o = 32; o > 0; o >>= 1) m = fmaxf(m, __shfl_xor(m, o));
                if ((tid & 63) == 0) wred[tid >> 6] = m;
            }
            __syncthreads();
            float mx = fmaxf(fmaxf(fmaxf(wred[0], wred[1]), fmaxf(wred[2], wred[3])),
                             fmaxf(fmaxf(wred[4], wred[5]), fmaxf(wred[6], wred[7])));
            if (tid < 512) {
                float e = expf(zv - mx);
                zl[tid] = e;
                float sm = e;
#pragma unroll
                for (int o = 32; o > 0; o >>= 1) sm += __shfl_xor(sm, o);
                if ((tid & 63) == 0) wred2[tid >> 6] = sm;
            }
            __syncthreads();
            float ssum = ((wred2[0] + wred2[1]) + (wred2[2] + wred2[3]))
                       + ((wred2[4] + wred2[5]) + (wred2[6] + wred2[7]));
            float inv = 1.0f / ssum;

            float acc = 0.f;
#pragma unroll 8
            for (int i = 0; i < 32; ++i)
                acc += zl[q * 32 + i] * eW[q * 32 + i][jj];
            red16[q][jj] = acc;
            __syncthreads();
            if (tid < 64) {
                float v = 0.f;
#pragma unroll
                for (int r = 0; r < 16; ++r) v += red16[r][jj];
                v = v * inv + cemb[((size_t)tstep * 32 + b) * 512 + s * 64 + jj];
                v = fmaxf(v, 0.f);
                comb_g[((size_t)tstep * 32 + b) * 512 + s * 64 + jj] = v;
                astore(combS + b * 512 + s * 64 + jj, v);
            }
        }
        ++nbar; bar_arrive(barb); bar_wait(barb, nbar * 8u);

        if (tid < 512) csh[tid] = aload(combS + b * 512 + tid);
        __syncthreads();
        {
            float acc = acc_hh;
#pragma unroll 8
            for (int i = 0; i < 32; ++i) {
                int k = kq * 4 + i * 16;
                float4 w4 = *reinterpret_cast<const float4*>(wip + k);
                acc += w4.x * csh[k]     + w4.y * csh[k + 1]
                     + w4.z * csh[k + 2] + w4.w * csh[k + 3];
            }
            acc += __shfl_xor(acc, 1);
            acc += __shfl_xor(acc, 2);
            if (kq == 0) sgate[g][jgl] = acc;
        }
        __syncthreads();
        if (tid < 64) {
            int jg = s * 64 + tid;
            float gi = sgate[0][tid] + bih[jg] + bhh[jg];
            float gf = sgate[1][tid] + bih[512 + jg] + bhh[512 + jg];
            float gg = sgate[2][tid] + bih[1024 + jg] + bhh[1024 + jg];
            float go = sgate[3][tid] + bih[1536 + jg] + bhh[1536 + jg];
            float c = carr[tid];
            float cn = sigf(gf) * c + sigf(gi) * tanhf(gg);
            float hn = sigf(go) * tanhf(cn);
            carr[tid] = cn;
            astore(h_g + b * 512 + jg, hn);
            states[((size_t)b * 64 + tstep) * 512 + jg] = hn;
        }
        ++nbar; bar_arrive(barb); bar_wait(barb, nbar * 8u);
    }
}

// ---- fallback step A/B (used only if cooperative launch fails) -------------
__global__ __launch_bounds__(1024) void k_stepA(
    const float* __restrict__ WaT, const float* __restrict__ zemb_t,
    const float* __restrict__ cemb_t, const float* __restrict__ encWc,
    const float* __restrict__ h_g, float* __restrict__ comb_t,
    float* __restrict__ combT)
{
    int b = blockIdx.x, tid = threadIdx.x;
    int j = tid & 511, kh = tid >> 9;
    __shared__ float sh[512];
    __shared__ float zp[2][512];
    __shared__ float p[512];
    __shared__ float red[16];
    __shared__ float red2[16];

    if (tid < 512) sh[tid] = h_g[b * 512 + tid];
    __syncthreads();
    {
        float acc = 0.f;
        const float* hp = sh + kh * 256;
        const float* wp = WaT + (size_t)(kh * 256) * 512 + j;
#pragma unroll 4
        for (int k = 0; k < 256; ++k) acc += hp[k] * wp[(size_t)k * 512];
        zp[kh][j] = acc;
    }
    __syncthreads();
    float zv = 0.f;
    if (tid < 512) zv = zp[0][tid] + zp[1][tid] + zemb_t[b * 512 + tid];
    float m = (tid < 512) ? zv : NEGF;
#pragma unroll
    for (int o = 32; o > 0; o >>= 1) m = fmaxf(m, __shfl_xor(m, o));
    if ((tid & 63) == 0) red[tid >> 6] = m;
    __syncthreads();
    float mx = red[0];
#pragma unroll
    for (int w = 1; w < 16; ++w) mx = fmaxf(mx, red[w]);
    float e = (tid < 512) ? expf(zv - mx) : 0.f;
    float sm = e;
#pragma unroll
    for (int o = 32; o > 0; o >>= 1) sm += __shfl_xor(sm, o);
    if ((tid & 63) == 0) red2[tid >> 6] = sm;
    __syncthreads();
    float S = 0.f;
#pragma unroll
    for (int w = 0; w < 16; ++w) S += red2[w];
    if (tid < 512) p[tid] = e * (1.0f / S);
    __syncthreads();
    {
        float acc = 0.f;
        const float* pp = p + kh * 256;
        const float* ep = encWc + ((size_t)b << 18) + (size_t)(kh * 256) * 512 + j;
#pragma unroll 4
        for (int k = 0; k < 256; ++k) acc += pp[k] * ep[(size_t)k * 512];
        zp[kh][j] = acc;
    }
    __syncthreads();
    if (tid < 512) {
        float v = zp[0][tid] + zp[1][tid] + cemb_t[b * 512 + tid];
        v = fmaxf(v, 0.f);
        comb_t[b * 512 + tid] = v;
        combT[tid * 32 + b] = v;
    }
}

__global__ __launch_bounds__(512) void k_stepB(
    const float* __restrict__ Wih, const float* __restrict__ Whh,
    const float* __restrict__ bih, const float* __restrict__ bhh,
    const float* __restrict__ combT, const float* __restrict__ hTr,
    float* __restrict__ hTw, float* __restrict__ cT, float* __restrict__ h_g,
    float* __restrict__ states, int tstep)
{
    __shared__ float sg2[2][2][4][32];
    int tid = threadIdx.x, bid = blockIdx.x;
    {
        int bb = tid & 31, g = (tid >> 5) & 3, hf = (tid >> 7) & 1, j2 = tid >> 8;
        int jg = bid * 2 + j2;
        int grow = g * 512 + jg;
        const float* wi = Wih + (size_t)grow * 512 + hf * 256;
        const float* wh = Whh + (size_t)grow * 512 + hf * 256;
        const float* cb = combT + (size_t)hf * 256 * 32 + bb;
        const float* hb = hTr + (size_t)hf * 256 * 32 + bb;
        float acc = 0.f;
#pragma unroll 4
        for (int k4 = 0; k4 < 64; ++k4) {
            float4 wi4 = *reinterpret_cast<const float4*>(wi + k4 * 4);
            float4 wh4 = *reinterpret_cast<const float4*>(wh + k4 * 4);
            acc += wi4.x * cb[(k4 * 4 + 0) * 32] + wh4.x * hb[(k4 * 4 + 0) * 32];
            acc += wi4.y * cb[(k4 * 4 + 1) * 32] + wh4.y * hb[(k4 * 4 + 1) * 32];
            acc += wi4.z * cb[(k4 * 4 + 2) * 32] + wh4.z * hb[(k4 * 4 + 2) * 32];
            acc += wi4.w * cb[(k4 * 4 + 3) * 32] + wh4.w * hb[(k4 * 4 + 3) * 32];
        }
        sg2[hf][j2][g][bb] = acc;
    }
    __syncthreads();
    if (tid < 64) {
        int bb = tid & 31, j2 = tid >> 5;
        int jg = bid * 2 + j2;
        float gi = sg2[0][j2][0][bb] + sg2[1][j2][0][bb] + bih[jg] + bhh[jg];
        float gf = sg2[0][j2][1][bb] + sg2[1][j2][1][bb] + bih[512 + jg] + bhh[512 + jg];
        float gg = sg2[0][j2][2][bb] + sg2[1][j2][2][bb] + bih[1024 + jg] + bhh[1024 + jg];
        float go = sg2[0][j2][3][bb] + sg2[1][j2][3][bb] + bih[1536 + jg] + bhh[1536 + jg];
        float c = cT[jg * 32 + bb];
        float cn = sigf(gf) * c + sigf(gi) * tanhf(gg);
        float hn = sigf(go) * tanhf(cn);
        cT[jg * 32 + bb] = cn;
        hTw[jg * 32 + bb] = hn;
        h_g[bb * 512 + jg] = hn;
        states[((size_t)bb * 64 + tstep) * 512 + jg] = hn;
    }
}

// finalize: lps = x - log(sumexp); preds = EXACT fp32 argmax over candidates
// within tau of the approx max (deterministic; first-index tiebreak).
__global__ __launch_bounds__(256) void k_finalize(float* __restrict__ out0,
    const unsigned long long* __restrict__ keyr, const float* __restrict__ sumr,
    const float* __restrict__ pre, const float* __restrict__ Wo,
    const float* __restrict__ bo, float* __restrict__ preds)
{
    int r = blockIdx.x, tid = threadIdx.x;    // r = b*64 + t
    float lse = logf(sumr[r]);
    unsigned k2 = (unsigned)(keyr[r] >> 32);
    float topv = __uint_as_float((k2 & 0x80000000u) ? (k2 ^ 0x80000000u) : ~k2);
    float thr = topv - 0.01f;

    __shared__ int cand[32];
    __shared__ float cex[32];
    __shared__ int ncand;
    if (tid == 0) ncand = 0;
    __syncthreads();

    float4* row4 = reinterpret_cast<float4*>(out0 + (size_t)r * 32000);
    for (int i = tid; i < 8000; i += 256) {
        float4 v = row4[i];
        if (v.x >= thr) { int p = atomicAdd(&ncand, 1); if (p < 32) cand[p] = i * 4; }
        if (v.y >= thr) { int p = atomicAdd(&ncand, 1); if (p < 32) cand[p] = i * 4 + 1; }
        if (v.z >= thr) { int p = atomicAdd(&ncand, 1); if (p < 32) cand[p] = i * 4 + 2; }
        if (v.w >= thr) { int p = atomicAdd(&ncand, 1); if (p < 32) cand[p] = i * 4 + 3; }
        v.x -= lse; v.y -= lse; v.z -= lse; v.w -= lse;
        row4[i] = v;
    }
    __syncthreads();
    int nc = min(ncand, 32);
    int m = (r & 63) * 32 + (r >> 6);
    const float* ap = pre + (size_t)m * 512;
    int w = tid >> 6, l = tid & 63;
    for (int c = w; c < nc; c += 4) {
        const float* wp = Wo + (size_t)cand[c] * 512;
        float d = 0.f;
#pragma unroll
        for (int e = 0; e < 8; ++e) d += ap[l * 8 + e] * wp[l * 8 + e];
#pragma unroll
        for (int o = 32; o > 0; o >>= 1) d += __shfl_xor(d, o);
        if (l == 0) cex[c] = d + bo[cand[c]];
    }
    __syncthreads();
    if (tid == 0) {
        float bv = NEGF; int bi = 0x7fffffff;
        for (int c = 0; c < nc; ++c) {
            float e = cex[c]; int ix = cand[c];
            if (e > bv || (e == bv && ix < bi)) { bv = e; bi = ix; }
        }
        preds[r] = (float)bi;
    }
}

__global__ __launch_bounds__(64) void k_masks(const float* __restrict__ preds,
    float* __restrict__ masks)
{
    int b = threadIdx.x;
    if (b < 32) {
        float mask = 1.0f;
        for (int t = 0; t < 64; ++t) {
            masks[b * 64 + t] = mask;
            if (preds[b * 64 + t] == 2.0f) mask = 0.0f;
        }
    }
}

extern "C" void kernel_launch(void* const* d_in, const int* in_sizes, int n_in,
                              void* d_out, int out_size, void* d_ws, size_t ws_size,
                              hipStream_t stream)
{
    (void)in_sizes; (void)n_in; (void)out_size; (void)ws_size;
    const float* enc  = (const float*)d_in[0];
    const float* ench = (const float*)d_in[1];
    const float* encc = (const float*)d_in[2];
    const int*   trg  = (const int*)d_in[3];
    const float* emb  = (const float*)d_in[5];
    const float* Wa   = (const float*)d_in[6];
    const float* ba   = (const float*)d_in[7];
    const float* Wc   = (const float*)d_in[8];
    const float* bc   = (const float*)d_in[9];
    const float* Wh0  = (const float*)d_in[10];
    const float* Wc0  = (const float*)d_in[11];
    const float* Wih  = (const float*)d_in[12];
    const float* Whh  = (const float*)d_in[13];
    const float* bih  = (const float*)d_in[14];
    const float* bhh  = (const float*)d_in[15];
    const float* Wp   = (const float*)d_in[16];
    const float* bp   = (const float*)d_in[17];
    const float* Wo   = (const float*)d_in[18];
    const float* bo   = (const float*)d_in[19];

    float* ws = (float*)d_ws;                 // ~26.7 MB of f32 scratch
    float* WaT   = ws;                        // 512*512
    float* eseq  = ws + 262144;               // 2048*512
    float* zemb  = ws + 1310720;              // 2048*512
    float* cemb  = ws + 2359296;              // 2048*512
    float* comb  = ws + 3407872;              // 2048*512
    float* pre   = ws + 4456448;              // 2048*512
    float* h_g   = ws + 5505024;              // 32*512
    float* hT0   = ws + 5521408;              // 512*32 (fallback)
    float* hT1   = ws + 5537792;              // 512*32 (fallback)
    float* cT    = ws + 5554176;              // 512*32
    float* z_g   = ws + 5570560;              // 32*512
    float* combS = ws + 5586944;              // 32*512
    unsigned* bar = (unsigned*)(ws + 5603328);// 4 KB: 32 groups x 32 uints
    unsigned long long* keyr = (unsigned long long*)(ws + 5604352);  // 2048 u64
    float* sumr  = ws + 5608448;              // 2048 f32
    unsigned short* Asp = (unsigned short*)(ws + 5610496);  // 2048*1024 bf16 = 4 MB

    float* out0 = (float*)d_out;              // lps  (32,64,32000)
    float* out1 = out0 + 65536000ull;         // preds (32,64) as float
    float* out2 = out1 + 2048;                // states (32,64,512)
    float* out3 = out2 + 1048576;             // masks (32,64) as float

    float* encWcB = out0;                     // staged in unwritten logits region

    // ---- prep ----
    k_transpose<<<dim3(16, 16), 256, 0, stream>>>(Wa, WaT, 512, 512, 1024, 512);
    k_init_state<<<32, 512, 0, stream>>>(ench, Wh0, h_g, hT0);
    k_init_state<<<32, 512, 0, stream>>>(encc, Wc0, nullptr, cT);
    k_gather<<<1024, 256, 0, stream>>>(trg, emb, eseq);
    k_gemm_nt<<<dim3(8, 4, 1), 256, 0, stream>>>(eseq, 512, 0, Wa, 1024, ba, zemb, 0, 512, 512, nullptr);
    k_gemm_nt<<<dim3(8, 4, 1), 256, 0, stream>>>(eseq, 512, 0, Wc, 1024, bc, cemb, 0, 512, 512, nullptr);
    k_gemm_nt<<<dim3(2, 4, 32), 256, 0, stream>>>(enc, 512, (size_t)262144, Wc + 512, 1024,
                                                  nullptr, encWcB, (size_t)262144, 512, 512, nullptr);
    hipMemsetAsync(bar, 0, 4096, stream);
    hipMemsetAsync(keyr, 0, 2048 * 8 + 2048 * 4, stream);

    // ---- fused recurrence: cooperative launch; fallback = 2-launch/step ----
    {
        const float* a0 = WaT;  const float* a1 = zemb; const float* a2 = cemb;
        const float* a3 = encWcB; const float* a4 = Wih; const float* a5 = Whh;
        const float* a6 = bih;  const float* a7 = bhh;
        float* a8 = h_g;  const float* a9 = cT; float* a10 = z_g; float* a11 = combS;
        float* a12 = comb; float* a13 = out2;
        unsigned* a14 = bar;
        void* args[] = { &a0,&a1,&a2,&a3,&a4,&a5,&a6,&a7,&a8,&a9,&a10,&a11,
                         &a12,&a13,&a14 };
        hipError_t e = hipLaunchCooperativeKernel((const void*)k_fused, dim3(256), dim3(1024),
                                                  args, 0, stream);
        if (e != hipSuccess) {
            (void)hipGetLastError();
            for (int t = 0; t < 64; ++t) {
                k_stepA<<<32, 1024, 0, stream>>>(WaT, zemb + (size_t)t * 32 * 512,
                                                 cemb + (size_t)t * 32 * 512, encWcB, h_g,
                                                 comb + (size_t)t * 32 * 512, combS);
                const float* hTr = (t & 1) ? hT1 : hT0;
                float*       hTw = (t & 1) ? hT0 : hT1;
                k_stepB<<<256, 512, 0, stream>>>(Wih, Whh, bih, bhh, combS, hTr, hTw, cT,
                                                 h_g, out2, t);
            }
        }
    }

    // ---- output projection (fp32, fused bf16 split) + MFMA logits + finalize ----
    k_gemm_nt<<<dim3(8, 4, 1), 256, 0, stream>>>(comb, 512, 0, Wp, 512, bp, pre, 0, 512, 512, Asp);
    k_mfma<<<dim3(8, 250), 256, 0, stream>>>(Asp, Wo, bo, out0, keyr, sumr);
    k_finalize<<<2048, 256, 0, stream>>>(out0, keyr, sumr, pre, Wo, bo, out1);
    k_masks<<<1, 64, 0, stream>>>(out1, out3);
}

// Round 16
// 1956.922 us; speedup vs baseline: 1.0471x; 1.0471x over previous
//
#include <hip/hip_runtime.h>

// Seq2Seq attention-LSTM decoder, B=32, T_ENC=512, H=E=ENC_H=512, V=32000, STEPS=64.
// Round 16: best-measured configuration. k_fused = round-13 (1059-1071 us).
// k_mfma = round-13 (grid 16x250, 48KB LDS, ~300 us). splitA fused into the
// Wp GEMM epilogue (round-14, verified safe) - removes one dispatch vs r13.

#define NEGF (-3.4028235e38f)

typedef short bf8 __attribute__((ext_vector_type(8)));
typedef unsigned short us8 __attribute__((ext_vector_type(8)));
typedef float f32x4 __attribute__((ext_vector_type(4)));

static __device__ __forceinline__ float sigf(float x) { return 1.0f / (1.0f + expf(-x)); }

static __device__ __forceinline__ float aload(const float* p) {
    return __hip_atomic_load(p, __ATOMIC_RELAXED, __HIP_MEMORY_SCOPE_AGENT);
}
static __device__ __forceinline__ void astore(float* p, float v) {
    __hip_atomic_store(p, v, __ATOMIC_RELAXED, __HIP_MEMORY_SCOPE_AGENT);
}
static __device__ __forceinline__ unsigned fordkey(float f) {
    unsigned u = __float_as_uint(f);
    return (u & 0x80000000u) ? ~u : (u | 0x80000000u);
}
static __device__ __forceinline__ unsigned short f2bf(float x) {  // RNE
    unsigned u = __float_as_uint(x);
    return (unsigned short)((u + 0x7FFFu + ((u >> 16) & 1u)) >> 16);
}
static __device__ __forceinline__ float bf2f(unsigned short b) {
    return __uint_as_float(((unsigned)b) << 16);
}

// ---- split group barrier: 8 blocks/group, monotonic counter, relaxed -------
static __device__ __forceinline__ void bar_arrive(unsigned* ctr) {
    __syncthreads();
    if (threadIdx.x == 0) {
        asm volatile("s_waitcnt vmcnt(0)" ::: "memory");
        __hip_atomic_fetch_add(ctr, 1u, __ATOMIC_RELAXED, __HIP_MEMORY_SCOPE_AGENT);
    }
}
static __device__ __forceinline__ void bar_wait(unsigned* ctr, unsigned target) {
    if (threadIdx.x == 0) {
        while ((int)(__hip_atomic_load(ctr, __ATOMIC_RELAXED, __HIP_MEMORY_SCOPE_AGENT)
                     - target) < 0) {
            __builtin_amdgcn_s_sleep(1);
        }
    }
    __syncthreads();
}

// dst[c*rows + r] = src[r*ld + coff + c]
__global__ __launch_bounds__(256) void k_transpose(const float* __restrict__ src,
    float* __restrict__ dst, int rows, int cols, int ld, int coff)
{
    __shared__ float tile[32][33];
    int c0 = blockIdx.x * 32, r0 = blockIdx.y * 32;
    int tx = threadIdx.x & 31, ty = threadIdx.x >> 5;
#pragma unroll
    for (int i = 0; i < 32; i += 8)
        tile[ty + i][tx] = src[(size_t)(r0 + ty + i) * ld + coff + c0 + tx];
    __syncthreads();
#pragma unroll
    for (int i = 0; i < 32; i += 8)
        dst[(size_t)(c0 + ty + i) * rows + r0 + tx] = tile[tx][ty + i];
}

// dst[b,j] = dot(vec[b,:], W[j,:]); writes row-major (optional) + transposed
__global__ __launch_bounds__(512) void k_init_state(const float* __restrict__ vec,
    const float* __restrict__ W, float* __restrict__ dst, float* __restrict__ dstT)
{
    int b = blockIdx.x, j = threadIdx.x;
    __shared__ float sv[512];
    sv[j] = vec[b * 512 + j];
    __syncthreads();
    const float* wr = W + (size_t)j * 512;
    float a0 = 0, a1 = 0, a2 = 0, a3 = 0;
#pragma unroll 4
    for (int k = 0; k < 512; k += 4) {
        float4 w = *reinterpret_cast<const float4*>(wr + k);
        a0 += sv[k] * w.x; a1 += sv[k + 1] * w.y;
        a2 += sv[k + 2] * w.z; a3 += sv[k + 3] * w.w;
    }
    float v = (a0 + a1) + (a2 + a3);
    if (dst) dst[b * 512 + j] = v;
    dstT[j * 32 + b] = v;
}

// emb_seq[m=t*32+b, :] = (t==0) ? 0 : embedding[trg[b, t-1], :]
__global__ __launch_bounds__(256) void k_gather(const int* __restrict__ trg,
    const float* __restrict__ emb, float* __restrict__ eseq)
{
    int gid = blockIdx.x * 256 + threadIdx.x;
    int m = gid >> 7, e4 = gid & 127;
    int t = m >> 5, b = m & 31;
    float4 v = make_float4(0.f, 0.f, 0.f, 0.f);
    if (t > 0) {
        int row = trg[b * 64 + (t - 1)];
        v = *reinterpret_cast<const float4*>(emb + (size_t)row * 512 + e4 * 4);
    }
    *reinterpret_cast<float4*>(eseq + (size_t)m * 512 + e4 * 4) = v;
}

// fp32 GEMM (small mats): C[M,N] = A*B^T (+bias). 256x128 tile, 16x8 micro.
// asp != nullptr: also emit bf16 [hi|lo] split of C rows into asp[M][1024].
__global__ __launch_bounds__(256) void k_gemm_nt(const float* __restrict__ A, int lda,
    size_t strideA, const float* __restrict__ B, int ldb, const float* __restrict__ bias,
    float* __restrict__ C, size_t strideC, int N, int K, unsigned short* __restrict__ asp)
{
    __shared__ float sA[32][260];
    __shared__ float sB[32][132];
    A += strideA * blockIdx.z;
    C += strideC * blockIdx.z;
    int tid = threadIdx.x;
    int m0 = blockIdx.x * 256, n0 = blockIdx.y * 128;
    int tx = tid & 15, ty = tid >> 4;
    float acc[16][8] = {};
    for (int k0 = 0; k0 < K; k0 += 32) {
#pragma unroll
        for (int i = 0; i < 8; ++i) {
            int f4 = tid + i * 256;
            int r = f4 >> 3, c4 = f4 & 7;
            float4 va = *reinterpret_cast<const float4*>(A + (size_t)(m0 + r) * lda + k0 + c4 * 4);
            sA[c4 * 4 + 0][r] = va.x; sA[c4 * 4 + 1][r] = va.y;
            sA[c4 * 4 + 2][r] = va.z; sA[c4 * 4 + 3][r] = va.w;
        }
#pragma unroll
        for (int i = 0; i < 4; ++i) {
            int f4 = tid + i * 256;
            int r = f4 >> 3, c4 = f4 & 7;
            float4 vb = *reinterpret_cast<const float4*>(B + (size_t)(n0 + r) * ldb + k0 + c4 * 4);
            sB[c4 * 4 + 0][r] = vb.x; sB[c4 * 4 + 1][r] = vb.y;
            sB[c4 * 4 + 2][r] = vb.z; sB[c4 * 4 + 3][r] = vb.w;
        }
        __syncthreads();
#pragma unroll 4
        for (int k = 0; k < 32; ++k) {
            float a[16], b[8];
            *reinterpret_cast<float4*>(&a[0])  = *reinterpret_cast<const float4*>(&sA[k][ty * 16]);
            *reinterpret_cast<float4*>(&a[4])  = *reinterpret_cast<const float4*>(&sA[k][ty * 16 + 4]);
            *reinterpret_cast<float4*>(&a[8])  = *reinterpret_cast<const float4*>(&sA[k][ty * 16 + 8]);
            *reinterpret_cast<float4*>(&a[12]) = *reinterpret_cast<const float4*>(&sA[k][ty * 16 + 12]);
            *reinterpret_cast<float4*>(&b[0]) = *reinterpret_cast<const float4*>(&sB[k][tx * 8]);
            *reinterpret_cast<float4*>(&b[4]) = *reinterpret_cast<const float4*>(&sB[k][tx * 8 + 4]);
#pragma unroll
            for (int i = 0; i < 16; ++i)
#pragma unroll
                for (int j = 0; j < 8; ++j)
                    acc[i][j] += a[i] * b[j];
        }
        __syncthreads();
    }
#pragma unroll
    for (int i = 0; i < 16; ++i) {
        int row = m0 + ty * 16 + i;
        float* cp = C + (size_t)row * N + n0 + tx * 8;
        float v[8];
#pragma unroll
        for (int j = 0; j < 8; ++j) v[j] = acc[i][j];
        if (bias) {
            const float* bb = bias + n0 + tx * 8;
#pragma unroll
            for (int j = 0; j < 8; ++j) v[j] += bb[j];
        }
        *reinterpret_cast<float4*>(cp) = make_float4(v[0], v[1], v[2], v[3]);
        *reinterpret_cast<float4*>(cp + 4) = make_float4(v[4], v[5], v[6], v[7]);
        if (asp) {
            unsigned short hi[8], lo[8];
#pragma unroll
            for (int j = 0; j < 8; ++j) {
                hi[j] = f2bf(v[j]);
                lo[j] = f2bf(v[j] - bf2f(hi[j]));
            }
            unsigned short* ap = asp + (size_t)row * 1024 + n0 + tx * 8;
            *reinterpret_cast<us8*>(ap)       = *reinterpret_cast<const us8*>(hi);
            *reinterpret_cast<us8*>(ap + 512) = *reinterpret_cast<const us8*>(lo);
        }
    }
}

// bf16 MFMA logits GEMM (round-13 version): C = [Ahi|Alo] @ [Bhi|Bhi]^T + bo.
// Tile 128x128, 256 thr (2x2 waves, 64x64/wave), 8 k-blocks of 64; B staged
// once per k-block, reused by both A segments. REMAP store + approx stats.
__global__ __launch_bounds__(256) void k_mfma(
    const unsigned short* __restrict__ Asp,  // [2048][1024] bf16 [hi|lo]
    const float* __restrict__ Wo,            // [32000][512] f32
    const float* __restrict__ bo,
    float* __restrict__ out0,
    unsigned long long* __restrict__ keyr, float* __restrict__ sumr)
{
    __shared__ unsigned short sAb[2][128 * 64];  // 32 KB (hi, lo), XOR-swizzled
    __shared__ unsigned short sBb[128 * 64];     // 16 KB
    int tid = threadIdx.x;
    int m0 = blockIdx.x * 128, n0 = blockIdx.y * 128;
    int l = tid & 63, wv = tid >> 6;
    int wr = wv >> 1, wc = wv & 1;
    int lm = l & 15, lg = l >> 4;

    f32x4 acc[4][4] = {};

    for (int kb = 0; kb < 8; ++kb) {
#pragma unroll
        for (int i = 0; i < 8; ++i) {
            int p = tid + i * 256;
            int seg = p >> 10;
            int q2 = p & 1023;
            int row = q2 >> 3, pk = q2 & 7;
            int widx = row * 64 + ((pk * 8) ^ ((row & 7) << 3));
            *reinterpret_cast<us8*>(&sAb[seg][widx]) =
                *reinterpret_cast<const us8*>(
                    Asp + (size_t)(m0 + row) * 1024 + seg * 512 + kb * 64 + pk * 8);
        }
#pragma unroll
        for (int i = 0; i < 4; ++i) {
            int p = tid + i * 256;
            int row = p >> 3, pk = p & 7;
            int widx = row * 64 + ((pk * 8) ^ ((row & 7) << 3));
            const float* bp = Wo + (size_t)(n0 + row) * 512 + kb * 64 + pk * 8;
            float4 b0 = *reinterpret_cast<const float4*>(bp);
            float4 b1 = *reinterpret_cast<const float4*>(bp + 4);
            unsigned short hw[8] = { f2bf(b0.x), f2bf(b0.y), f2bf(b0.z), f2bf(b0.w),
                                     f2bf(b1.x), f2bf(b1.y), f2bf(b1.z), f2bf(b1.w) };
            *reinterpret_cast<us8*>(&sBb[widx]) = *reinterpret_cast<const us8*>(hw);
        }
        __syncthreads();
#pragma unroll
        for (int ks = 0; ks < 2; ++ks) {
            bf8 bfr[4];
#pragma unroll
            for (int fc = 0; fc < 4; ++fc) {
                int row = wc * 64 + fc * 16 + lm;
                int idx = row * 64 + ((ks * 32 + lg * 8) ^ ((row & 7) << 3));
                bfr[fc] = *reinterpret_cast<const bf8*>(&sBb[idx]);
            }
#pragma unroll
            for (int aseg = 0; aseg < 2; ++aseg) {
                bf8 af[4];
#pragma unroll
                for (int fr = 0; fr < 4; ++fr) {
                    int row = wr * 64 + fr * 16 + lm;
                    int idx = row * 64 + ((ks * 32 + lg * 8) ^ ((row & 7) << 3));
                    af[fr] = *reinterpret_cast<const bf8*>(&sAb[aseg][idx]);
                }
#pragma unroll
                for (int fr = 0; fr < 4; ++fr)
#pragma unroll
                    for (int fc = 0; fc < 4; ++fc)
                        acc[fr][fc] = __builtin_amdgcn_mfma_f32_16x16x32_bf16(
                            af[fr], bfr[fc], acc[fr][fc], 0, 0, 0);
            }
        }
        __syncthreads();
    }

#pragma unroll
    for (int fr = 0; fr < 4; ++fr) {
#pragma unroll
        for (int j = 0; j < 4; ++j) {
            int m = m0 + wr * 64 + fr * 16 + lg * 4 + j;
            size_t crow = (size_t)((m & 31) * 64 + (m >> 5));
            float* cp = out0 + crow * 32000 + n0 + wc * 64 + lm;
            float vv[4];
            float mval = NEGF; int midx = 0; float esum = 0.f;
#pragma unroll
            for (int fc = 0; fc < 4; ++fc) {
                int col = n0 + wc * 64 + fc * 16 + lm;
                float v = acc[fr][fc][j] + bo[col];
                vv[fc] = v;
                if (v > mval) { mval = v; midx = col; }
                esum += expf(v);
            }
#pragma unroll
            for (int fc = 0; fc < 4; ++fc) cp[fc * 16] = vv[fc];
#pragma unroll
            for (int msk = 1; msk <= 8; msk <<= 1) {
                float vo = __shfl_xor(mval, msk);
                int   io = __shfl_xor(midx, msk);
                float so = __shfl_xor(esum, msk);
                esum += so;
                if (vo > mval || (vo == mval && io < midx)) { mval = vo; midx = io; }
            }
            if (lm == 0) {
                unsigned long long key =
                    ((unsigned long long)fordkey(mval) << 32) | (unsigned)(~(unsigned)midx);
                atomicMax(&keyr[crow], key);
                atomicAdd(&sumr[crow], esum);
            }
        }
    }
}

// ---------------- fused 64-step decoder (cooperative, per-b groups) --------
// round-13 version, verbatim (proven 1059-1071 us).
__global__ __launch_bounds__(1024) void k_fused(
    const float* __restrict__ WaT, const float* __restrict__ zemb,
    const float* __restrict__ cemb, const float* __restrict__ encWc,
    const float* __restrict__ Wih, const float* __restrict__ Whh,
    const float* __restrict__ bih, const float* __restrict__ bhh,
    float* __restrict__ h_g, const float* __restrict__ cT,
    float* __restrict__ z_g, float* __restrict__ combS,
    float* __restrict__ comb_g, float* __restrict__ states,
    unsigned* __restrict__ bar)
{
    __shared__ float eW[512][64];
    __shared__ float hsh[512];
    __shared__ float csh[512];
    __shared__ float zl[512];
    __shared__ float red16[16][64];
    __shared__ float wred[8];
    __shared__ float wred2[8];
    __shared__ float sgate[4][64];
    __shared__ float carr[64];

    int tid = threadIdx.x, bid = blockIdx.x;
    int b = bid >> 3, s = bid & 7;
    int jj = tid & 63, q = tid >> 6;
    unsigned* barb = bar + b * 32;
    unsigned nbar = 0;

    int wv = tid >> 6, lane = tid & 63;
    int rowid = wv * 16 + (lane >> 2);
    int g = rowid >> 6, jgl = rowid & 63;
    int kq = lane & 3;
    const float* whp = Whh + (size_t)(g * 512 + s * 64 + jgl) * 512;
    const float* wip = Wih + (size_t)(g * 512 + s * 64 + jgl) * 512;

    {
        const float* src = encWc + ((size_t)b << 18) + s * 64;
        for (int i = tid; i < 512 * 16; i += 1024) {
            int t = i >> 4, c4 = i & 15;
            float4 v = *reinterpret_cast<const float4*>(src + (size_t)t * 512 + c4 * 4);
            *reinterpret_cast<float4*>(&eW[t][c4 * 4]) = v;
        }
    }
    if (tid < 64) carr[tid] = cT[(s * 64 + tid) * 32 + b];

    for (int tstep = 0; tstep < 64; ++tstep) {
        if (tid < 512) hsh[tid] = aload(h_g + b * 512 + tid);
        __syncthreads();
        {
            float acc = 0.f;
            const float* hp = hsh + q * 32;
            const float* wp = WaT + (size_t)(q * 32) * 512 + s * 64 + jj;
#pragma unroll 8
            for (int k = 0; k < 32; ++k)
                acc += hp[k] * wp[(size_t)k * 512];
            red16[q][jj] = acc;
        }
        __syncthreads();
        if (tid < 64) {
            float v = 0.f;
#pragma unroll
            for (int r = 0; r < 16; ++r) v += red16[r][jj];
            v += zemb[((size_t)tstep * 32 + b) * 512 + s * 64 + jj];
            astore(z_g + b * 512 + s * 64 + jj, v);
        }
        ++nbar; bar_arrive(barb);

        float acc_hh = 0.f;
#pragma unroll 8
        for (int i = 0; i < 32; ++i) {
            int k = kq * 4 + i * 16;
            float4 v4 = *reinterpret_cast<const float4*>(whp + k);
            acc_hh += v4.x * hsh[k]     + v4.y * hsh[k + 1]
                    + v4.z * hsh[k + 2] + v4.w * hsh[k + 3];
        }
        bar_wait(barb, nbar * 8u);

        {
            float zv = 0.f;
            if (tid < 512) {
                zv = aload(z_g + b * 512 + tid);
                float m = zv;
#pragma unroll
                for (int o = 32; o > 0; o >>= 1) m = fmaxf(m, __shfl_xor(m, o));
                if ((tid & 63) == 0) wred[tid >> 6] = m;
            }
            __syncthreads();
            float mx = fmaxf(fmaxf(fmaxf(wred[0], wred[1]), fmaxf(wred[2], wred[3])),
                             fmaxf(fmaxf(wred[4], wred[5]), fmaxf(wred[6], wred[7])));
            if (tid < 512) {
                float e = expf(zv - mx);
                zl[tid] = e;
                float sm = e;
#pragma unroll
                for (int o = 32; o > 0; o >>= 1) sm += __shfl_xor(sm, o);
                if ((tid & 63) == 0) wred2[tid >> 6] = sm;
            }
            __syncthreads();
            float ssum = ((wred2[0] + wred2[1]) + (wred2[2] + wred2[3]))
                       + ((wred2[4] + wred2[5]) + (wred2[6] + wred2[7]));
            float inv = 1.0f / ssum;

            float acc = 0.f;
#pragma unroll 8
            for (int i = 0; i < 32; ++i)
                acc += zl[q * 32 + i] * eW[q * 32 + i][jj];
            red16[q][jj] = acc;
            __syncthreads();
            if (tid < 64) {
                float v = 0.f;
#pragma unroll
                for (int r = 0; r < 16; ++r) v += red16[r][jj];
                v = v * inv + cemb[((size_t)tstep * 32 + b) * 512 + s * 64 + jj];
                v = fmaxf(v, 0.f);
                comb_g[((size_t)tstep * 32 + b) * 512 + s * 64 + jj] = v;
                astore(combS + b * 512 + s * 64 + jj, v);
            }
        }
        ++nbar; bar_arrive(barb); bar_wait(barb, nbar * 8u);

        if (tid < 512) csh[tid] = aload(combS + b * 512 + tid);
        __syncthreads();
        {
            float acc = acc_hh;
#pragma unroll 8
            for (int i = 0; i < 32; ++i) {
                int k = kq * 4 + i * 16;
                float4 w4 = *reinterpret_cast<const float4*>(wip + k);
                acc += w4.x * csh[k]     + w4.y * csh[k + 1]
                     + w4.z * csh[k + 2] + w4.w * csh[k + 3];
            }
            acc += __shfl_xor(acc, 1);
            acc += __shfl_xor(acc, 2);
            if (kq == 0) sgate[g][jgl] = acc;
        }
        __syncthreads();
        if (tid < 64) {
            int jg = s * 64 + tid;
            float gi = sgate[0][tid] + bih[jg] + bhh[jg];
            float gf = sgate[1][tid] + bih[512 + jg] + bhh[512 + jg];
            float gg = sgate[2][tid] + bih[1024 + jg] + bhh[1024 + jg];
            float go = sgate[3][tid] + bih[1536 + jg] + bhh[1536 + jg];
            float c = carr[tid];
            float cn = sigf(gf) * c + sigf(gi) * tanhf(gg);
            float hn = sigf(go) * tanhf(cn);
            carr[tid] = cn;
            astore(h_g + b * 512 + jg, hn);
            states[((size_t)b * 64 + tstep) * 512 + jg] = hn;
        }
        ++nbar; bar_arrive(barb); bar_wait(barb, nbar * 8u);
    }
}

// ---- fallback step A/B (used only if cooperative launch fails) -------------
__global__ __launch_bounds__(1024) void k_stepA(
    const float* __restrict__ WaT, const float* __restrict__ zemb_t,
    const float* __restrict__ cemb_t, const float* __restrict__ encWc,
    const float* __restrict__ h_g, float* __restrict__ comb_t,
    float* __restrict__ combT)
{
    int b = blockIdx.x, tid = threadIdx.x;
    int j = tid & 511, kh = tid >> 9;
    __shared__ float sh[512];
    __shared__ float zp[2][512];
    __shared__ float p[512];
    __shared__ float red[16];
    __shared__ float red2[16];

    if (tid < 512) sh[tid] = h_g[b * 512 + tid];
    __syncthreads();
    {
        float acc = 0.f;
        const float* hp = sh + kh * 256;
        const float* wp = WaT + (size_t)(kh * 256) * 512 + j;
#pragma unroll 4
        for (int k = 0; k < 256; ++k) acc += hp[k] * wp[(size_t)k * 512];
        zp[kh][j] = acc;
    }
    __syncthreads();
    float zv = 0.f;
    if (tid < 512) zv = zp[0][tid] + zp[1][tid] + zemb_t[b * 512 + tid];
    float m = (tid < 512) ? zv : NEGF;
#pragma unroll
    for (int o = 32; o > 0; o >>= 1) m = fmaxf(m, __shfl_xor(m, o));
    if ((tid & 63) == 0) red[tid >> 6] = m;
    __syncthreads();
    float mx = red[0];
#pragma unroll
    for (int w = 1; w < 16; ++w) mx = fmaxf(mx, red[w]);
    float e = (tid < 512) ? expf(zv - mx) : 0.f;
    float sm = e;
#pragma unroll
    for (int o = 32; o > 0; o >>= 1) sm += __shfl_xor(sm, o);
    if ((tid & 63) == 0) red2[tid >> 6] = sm;
    __syncthreads();
    float S = 0.f;
#pragma unroll
    for (int w = 0; w < 16; ++w) S += red2[w];
    if (tid < 512) p[tid] = e * (1.0f / S);
    __syncthreads();
    {
        float acc = 0.f;
        const float* pp = p + kh * 256;
        const float* ep = encWc + ((size_t)b << 18) + (size_t)(kh * 256) * 512 + j;
#pragma unroll 4
        for (int k = 0; k < 256; ++k) acc += pp[k] * ep[(size_t)k * 512];
        zp[kh][j] = acc;
    }
    __syncthreads();
    if (tid < 512) {
        float v = zp[0][tid] + zp[1][tid] + cemb_t[b * 512 + tid];
        v = fmaxf(v, 0.f);
        comb_t[b * 512 + tid] = v;
        combT[tid * 32 + b] = v;
    }
}

__global__ __launch_bounds__(512) void k_stepB(
    const float* __restrict__ Wih, const float* __restrict__ Whh,
    const float* __restrict__ bih, const float* __restrict__ bhh,
    const float* __restrict__ combT, const float* __restrict__ hTr,
    float* __restrict__ hTw, float* __restrict__ cT, float* __restrict__ h_g,
    float* __restrict__ states, int tstep)
{
    __shared__ float sg2[2][2][4][32];
    int tid = threadIdx.x, bid = blockIdx.x;
    {
        int bb = tid & 31, g = (tid >> 5) & 3, hf = (tid >> 7) & 1, j2 = tid >> 8;
        int jg = bid * 2 + j2;
        int grow = g * 512 + jg;
        const float* wi = Wih + (size_t)grow * 512 + hf * 256;
        const float* wh = Whh + (size_t)grow * 512 + hf * 256;
        const float* cb = combT + (size_t)hf * 256 * 32 + bb;
        const float* hb = hTr + (size_t)hf * 256 * 32 + bb;
        float acc = 0.f;
#pragma unroll 4
        for (int k4 = 0; k4 < 64; ++k4) {
            float4 wi4 = *reinterpret_cast<const float4*>(wi + k4 * 4);
            float4 wh4 = *reinterpret_cast<const float4*>(wh + k4 * 4);
            acc += wi4.x * cb[(k4 * 4 + 0) * 32] + wh4.x * hb[(k4 * 4 + 0) * 32];
            acc += wi4.y * cb[(k4 * 4 + 1) * 32] + wh4.y * hb[(k4 * 4 + 1) * 32];
            acc += wi4.z * cb[(k4 * 4 + 2) * 32] + wh4.z * hb[(k4 * 4 + 2) * 32];
            acc += wi4.w * cb[(k4 * 4 + 3) * 32] + wh4.w * hb[(k4 * 4 + 3) * 32];
        }
        sg2[hf][j2][g][bb] = acc;
    }
    __syncthreads();
    if (tid < 64) {
        int bb = tid & 31, j2 = tid >> 5;
        int jg = bid * 2 + j2;
        float gi = sg2[0][j2][0][bb] + sg2[1][j2][0][bb] + bih[jg] + bhh[jg];
        float gf = sg2[0][j2][1][bb] + sg2[1][j2][1][bb] + bih[512 + jg] + bhh[512 + jg];
        float gg = sg2[0][j2][2][bb] + sg2[1][j2][2][bb] + bih[1024 + jg] + bhh[1024 + jg];
        float go = sg2[0][j2][3][bb] + sg2[1][j2][3][bb] + bih[1536 + jg] + bhh[1536 + jg];
        float c = cT[jg * 32 + bb];
        float cn = sigf(gf) * c + sigf(gi) * tanhf(gg);
        float hn = sigf(go) * tanhf(cn);
        cT[jg * 32 + bb] = cn;
        hTw[jg * 32 + bb] = hn;
        h_g[bb * 512 + jg] = hn;
        states[((size_t)bb * 64 + tstep) * 512 + jg] = hn;
    }
}

// finalize: lps = x - log(sumexp); preds = EXACT fp32 argmax over candidates
// within tau of the approx max (deterministic; first-index tiebreak).
__global__ __launch_bounds__(256) void k_finalize(float* __restrict__ out0,
    const unsigned long long* __restrict__ keyr, const float* __restrict__ sumr,
    const float* __restrict__ pre, const float* __restrict__ Wo,
    const float* __restrict__ bo, float* __restrict__ preds)
{
    int r = blockIdx.x, tid = threadIdx.x;    // r = b*64 + t
    float lse = logf(sumr[r]);
    unsigned k2 = (unsigned)(keyr[r] >> 32);
    float topv = __uint_as_float((k2 & 0x80000000u) ? (k2 ^ 0x80000000u) : ~k2);
    float thr = topv - 0.01f;

    __shared__ int cand[32];
    __shared__ float cex[32];
    __shared__ int ncand;
    if (tid == 0) ncand = 0;
    __syncthreads();

    float4* row4 = reinterpret_cast<float4*>(out0 + (size_t)r * 32000);
    for (int i = tid; i < 8000; i += 256) {
        float4 v = row4[i];
        if (v.x >= thr) { int p = atomicAdd(&ncand, 1); if (p < 32) cand[p] = i * 4; }
        if (v.y >= thr) { int p = atomicAdd(&ncand, 1); if (p < 32) cand[p] = i * 4 + 1; }
        if (v.z >= thr) { int p = atomicAdd(&ncand, 1); if (p < 32) cand[p] = i * 4 + 2; }
        if (v.w >= thr) { int p = atomicAdd(&ncand, 1); if (p < 32) cand[p] = i * 4 + 3; }
        v.x -= lse; v.y -= lse; v.z -= lse; v.w -= lse;
        row4[i] = v;
    }
    __syncthreads();
    int nc = min(ncand, 32);
    int m = (r & 63) * 32 + (r >> 6);
    const float* ap = pre + (size_t)m * 512;
    int w = tid >> 6, l = tid & 63;
    for (int c = w; c < nc; c += 4) {
        const float* wp = Wo + (size_t)cand[c] * 512;
        float d = 0.f;
#pragma unroll
        for (int e = 0; e < 8; ++e) d += ap[l * 8 + e] * wp[l * 8 + e];
#pragma unroll
        for (int o = 32; o > 0; o >>= 1) d += __shfl_xor(d, o);
        if (l == 0) cex[c] = d + bo[cand[c]];
    }
    __syncthreads();
    if (tid == 0) {
        float bv = NEGF; int bi = 0x7fffffff;
        for (int c = 0; c < nc; ++c) {
            float e = cex[c]; int ix = cand[c];
            if (e > bv || (e == bv && ix < bi)) { bv = e; bi = ix; }
        }
        preds[r] = (float)bi;
    }
}

__global__ __launch_bounds__(64) void k_masks(const float* __restrict__ preds,
    float* __restrict__ masks)
{
    int b = threadIdx.x;
    if (b < 32) {
        float mask = 1.0f;
        for (int t = 0; t < 64; ++t) {
            masks[b * 64 + t] = mask;
            if (preds[b * 64 + t] == 2.0f) mask = 0.0f;
        }
    }
}

extern "C" void kernel_launch(void* const* d_in, const int* in_sizes, int n_in,
                              void* d_out, int out_size, void* d_ws, size_t ws_size,
                              hipStream_t stream)
{
    (void)in_sizes; (void)n_in; (void)out_size; (void)ws_size;
    const float* enc  = (const float*)d_in[0];
    const float* ench = (const float*)d_in[1];
    const float* encc = (const float*)d_in[2];
    const int*   trg  = (const int*)d_in[3];
    const float* emb  = (const float*)d_in[5];
    const float* Wa   = (const float*)d_in[6];
    const float* ba   = (const float*)d_in[7];
    const float* Wc   = (const float*)d_in[8];
    const float* bc   = (const float*)d_in[9];
    const float* Wh0  = (const float*)d_in[10];
    const float* Wc0  = (const float*)d_in[11];
    const float* Wih  = (const float*)d_in[12];
    const float* Whh  = (const float*)d_in[13];
    const float* bih  = (const float*)d_in[14];
    const float* bhh  = (const float*)d_in[15];
    const float* Wp   = (const float*)d_in[16];
    const float* bp   = (const float*)d_in[17];
    const float* Wo   = (const float*)d_in[18];
    const float* bo   = (const float*)d_in[19];

    float* ws = (float*)d_ws;                 // ~26.7 MB of f32 scratch
    float* WaT   = ws;                        // 512*512
    float* eseq  = ws + 262144;               // 2048*512
    float* zemb  = ws + 1310720;              // 2048*512
    float* cemb  = ws + 2359296;              // 2048*512
    float* comb  = ws + 3407872;              // 2048*512
    float* pre   = ws + 4456448;              // 2048*512
    float* h_g   = ws + 5505024;              // 32*512
    float* hT0   = ws + 5521408;              // 512*32 (fallback)
    float* hT1   = ws + 5537792;              // 512*32 (fallback)
    float* cT    = ws + 5554176;              // 512*32
    float* z_g   = ws + 5570560;              // 32*512
    float* combS = ws + 5586944;              // 32*512
    unsigned* bar = (unsigned*)(ws + 5603328);// 4 KB: 32 groups x 32 uints
    unsigned long long* keyr = (unsigned long long*)(ws + 5604352);  // 2048 u64
    float* sumr  = ws + 5608448;              // 2048 f32
    unsigned short* Asp = (unsigned short*)(ws + 5610496);  // 2048*1024 bf16 = 4 MB

    float* out0 = (float*)d_out;              // lps  (32,64,32000)
    float* out1 = out0 + 65536000ull;         // preds (32,64) as float
    float* out2 = out1 + 2048;                // states (32,64,512)
    float* out3 = out2 + 1048576;             // masks (32,64) as float

    float* encWcB = out0;                     // staged in unwritten logits region

    // ---- prep ----
    k_transpose<<<dim3(16, 16), 256, 0, stream>>>(Wa, WaT, 512, 512, 1024, 512);
    k_init_state<<<32, 512, 0, stream>>>(ench, Wh0, h_g, hT0);
    k_init_state<<<32, 512, 0, stream>>>(encc, Wc0, nullptr, cT);
    k_gather<<<1024, 256, 0, stream>>>(trg, emb, eseq);
    k_gemm_nt<<<dim3(8, 4, 1), 256, 0, stream>>>(eseq, 512, 0, Wa, 1024, ba, zemb, 0, 512, 512, nullptr);
    k_gemm_nt<<<dim3(8, 4, 1), 256, 0, stream>>>(eseq, 512, 0, Wc, 1024, bc, cemb, 0, 512, 512, nullptr);
    k_gemm_nt<<<dim3(2, 4, 32), 256, 0, stream>>>(enc, 512, (size_t)262144, Wc + 512, 1024,
                                                  nullptr, encWcB, (size_t)262144, 512, 512, nullptr);
    hipMemsetAsync(bar, 0, 4096, stream);
    hipMemsetAsync(keyr, 0, 2048 * 8 + 2048 * 4, stream);

    // ---- fused recurrence: cooperative launch; fallback = 2-launch/step ----
    {
        const float* a0 = WaT;  const float* a1 = zemb; const float* a2 = cemb;
        const float* a3 = encWcB; const float* a4 = Wih; const float* a5 = Whh;
        const float* a6 = bih;  const float* a7 = bhh;
        float* a8 = h_g;  const float* a9 = cT; float* a10 = z_g; float* a11 = combS;
        float* a12 = comb; float* a13 = out2;
        unsigned* a14 = bar;
        void* args[] = { &a0,&a1,&a2,&a3,&a4,&a5,&a6,&a7,&a8,&a9,&a10,&a11,
                         &a12,&a13,&a14 };
        hipError_t e = hipLaunchCooperativeKernel((const void*)k_fused, dim3(256), dim3(1024),
                                                  args, 0, stream);
        if (e != hipSuccess) {
            (void)hipGetLastError();
            for (int t = 0; t < 64; ++t) {
                k_stepA<<<32, 1024, 0, stream>>>(WaT, zemb + (size_t)t * 32 * 512,
                                                 cemb + (size_t)t * 32 * 512, encWcB, h_g,
                                                 comb + (size_t)t * 32 * 512, combS);
                const float* hTr = (t & 1) ? hT1 : hT0;
                float*       hTw = (t & 1) ? hT0 : hT1;
                k_stepB<<<256, 512, 0, stream>>>(Wih, Whh, bih, bhh, combS, hTr, hTw, cT,
                                                 h_g, out2, t);
            }
        }
    }

    // ---- output projection (fp32, fused bf16 split) + MFMA logits + finalize ----
    k_gemm_nt<<<dim3(8, 4, 1), 256, 0, stream>>>(comb, 512, 0, Wp, 512, bp, pre, 0, 512, 512, Asp);
    k_mfma<<<dim3(16, 250), 256, 0, stream>>>(Asp, Wo, bo, out0, keyr, sumr);
    k_finalize<<<2048, 256, 0, stream>>>(out0, keyr, sumr, pre, Wo, bo, out1);
    k_masks<<<1, 64, 0, stream>>>(out1, out3);
}